// Round 1
// baseline (844.581 us; speedup 1.0000x reference)
//
#include <hip/hip_runtime.h>

// BRITS-style RNN (B=4096, T=256, D=36, H=64) on gfx950.
// Design: 256 blocks x 256 threads; block owns 16 rows for all T steps.
// All GEMMs via mfma_f32_16x16x32_bf16 with weights resident in VGPRs as
// bf16 B-fragments (loaded once). Activations staged in zero-padded bf16 LDS.
// Recurrent state h kept in f32 LDS; losses accumulated per-thread then
// block-reduced -> global atomics in d_ws; tiny finalize kernel writes loss.

#define Bsz 4096
#define Tn  256
#define Dn  36
#define Hn  64
#define EPSf 1e-5f

// LDS strides (elements)
#define DST 72    // dbuf / vcbuf / hbuf (shorts): 36 or 64 data + zero pad
#define CST 104   // cbuf (shorts): 72 data + zero pad to 96 + pad
#define XST 136   // xbuf (shorts): 108 data + zero pad to 128 + pad
#define HLST 65   // h_s (floats)

using f32x4 = __attribute__((ext_vector_type(4))) float;
using s8    = __attribute__((ext_vector_type(8))) short;

__device__ __forceinline__ short f2bf(float x) {
  unsigned u = __float_as_uint(x);
  unsigned r = (u + 0x7FFFu + ((u >> 16) & 1u)) >> 16;  // RNE
  return (short)r;
}
__device__ __forceinline__ float sigf(float x) { return 1.f / (1.f + __expf(-x)); }
__device__ __forceinline__ float tanhfast(float x) { return 1.f - 2.f / (1.f + __expf(2.f * x)); }

// ---------------- prepass: rmsum[t] = 1/(sum(masks[:,t,:]) + EPS) -------------
__global__ void msum_k(const float* __restrict__ masks, float* __restrict__ rmsum) {
  int t = blockIdx.x;
  float s = 0.f;
  for (int r = threadIdx.x; r < Bsz; r += 256) {
    const float* mp = masks + ((size_t)r * Tn + t) * Dn;
    #pragma unroll
    for (int d = 0; d < Dn; ++d) s += mp[d];
  }
  __shared__ float red[256];
  red[threadIdx.x] = s;
  __syncthreads();
  for (int k = 128; k > 0; k >>= 1) {
    if (threadIdx.x < k) red[threadIdx.x] += red[threadIdx.x + k];
    __syncthreads();
  }
  if (threadIdx.x == 0) rmsum[t] = 1.f / (red[0] + EPSf);
}

// ---------------- main ---------------------------------------------------------
__global__ __launch_bounds__(256, 1) void brits_main(
    const float* __restrict__ values, const float* __restrict__ masks,
    const float* __restrict__ deltas, const float* __restrict__ label,
    const float* __restrict__ is_train,
    const float* __restrict__ W_ih, const float* __restrict__ W_hh,
    const float* __restrict__ b_ih, const float* __restrict__ b_hh,
    const float* __restrict__ hist_W, const float* __restrict__ hist_b,
    const float* __restrict__ feat_W, const float* __restrict__ feat_b,
    const float* __restrict__ decay_W, const float* __restrict__ decay_b,
    const float* __restrict__ comb_W, const float* __restrict__ comb_b,
    const float* __restrict__ out_W, const float* __restrict__ out_b,
    float* __restrict__ out, const float* __restrict__ rmsum,
    float* __restrict__ ws_acc /* [0] il, [1] cls, [2] wsum */) {

  __shared__ float val_s[16 * 37];
  __shared__ float msk_s[16 * 37];
  __shared__ float h_s[16 * HLST];
  __shared__ float vx_s[16];
  __shared__ float histw_s[64];
  __shared__ float red_s[256];
  __shared__ short dbuf[16 * DST];   // delta bf16, K-pad zeros [36,64)
  __shared__ short vcbuf[16 * DST];  // value_c1 bf16
  __shared__ short cbuf[16 * CST];   // [gamma(0:36) | mask(36:72)] pad zeros [72,96)
  __shared__ short xbuf[16 * XST];   // [vc2(0:36) | mask(36:72) | gamma(72:108)] pad [108,128)
  __shared__ short hbuf[16 * DST];   // h bf16 (64 real)

  const int tid  = threadIdx.x;
  const int w    = tid >> 6;        // wave 0..3
  const int lane = tid & 63;
  const int lc   = lane & 15;       // A-row / B-col / D-col
  const int r4   = lane >> 4;       // k-group (A/B), row-group (D)
  const int bid  = blockIdx.x;
  const int row0 = bid * 16;

  // ---- init LDS ----
  for (int i = tid; i < 16 * DST; i += 256) { dbuf[i] = 0; vcbuf[i] = 0; hbuf[i] = 0; }
  for (int i = tid; i < 16 * CST; i += 256) cbuf[i] = 0;
  for (int i = tid; i < 16 * XST; i += 256) xbuf[i] = 0;
  for (int i = tid; i < 16 * HLST; i += 256) h_s[i] = 0.f;
  if (tid < 64) histw_s[tid] = hist_W[tid];

  // ---- weight fragments (persistent VGPRs) ----
  // B-frag convention: b[e] = Bmat[k=(lane>>4)*8 + 32*kt + e][n=16*ntile + lc],
  // where Bmat[k][n] = W[n][k] (we multiply by W^T).
  const int k0b = r4 * 8;
  s8 wih_f[3][4];
  s8 whh_f[3][2];
  #pragma unroll
  for (int g = 0; g < 3; ++g) {
    const int n = 64 * g + 16 * w + lc;   // gate row, < 192 always
    #pragma unroll
    for (int kt = 0; kt < 4; ++kt) {
      s8 f;
      #pragma unroll
      for (int e = 0; e < 8; ++e) {
        int k = k0b + 32 * kt + e;
        f[e] = (k < 108) ? f2bf(W_ih[n * 108 + k]) : (short)0;
      }
      wih_f[g][kt] = f;
    }
    #pragma unroll
    for (int kt = 0; kt < 2; ++kt) {
      s8 f;
      #pragma unroll
      for (int e = 0; e < 8; ++e) {
        int k = k0b + 32 * kt + e;
        f[e] = f2bf(W_hh[n * 64 + k]);
      }
      whh_f[g][kt] = f;
    }
  }
  const int  nsm = 16 * w + lc;                 // small-GEMM output col
  const bool act = (w < 3) && (nsm < Dn);
  s8 dec_f[2], feat_f[2], comb_f[3];
  #pragma unroll
  for (int kt = 0; kt < 2; ++kt) {
    s8 fd, ff;
    #pragma unroll
    for (int e = 0; e < 8; ++e) {
      int k = k0b + 32 * kt + e;
      float dv = (act && k < Dn) ? decay_W[nsm * Dn + k] : 0.f;
      float fv = (act && k < Dn && k != nsm) ? feat_W[nsm * Dn + k] : 0.f;  // zero diag
      fd[e] = f2bf(dv);
      ff[e] = f2bf(fv);
    }
    dec_f[kt] = fd; feat_f[kt] = ff;
  }
  #pragma unroll
  for (int kt = 0; kt < 3; ++kt) {
    s8 f;
    #pragma unroll
    for (int e = 0; e < 8; ++e) {
      int k = k0b + 32 * kt + e;
      f[e] = (act && k < 72) ? f2bf(comb_W[nsm * 72 + k]) : (short)0;
    }
    comb_f[kt] = f;
  }

  // per-lane biases
  const int dim = 16 * w + lc;                       // h dim, < 64
  const float db   = act ? decay_b[nsm] : 0.f;
  const float fb   = act ? feat_b[nsm] : 0.f;
  const float cbv  = act ? comb_b[nsm] : 0.f;
  const float br   = b_ih[dim] + b_hh[dim];
  const float bz   = b_ih[64 + dim] + b_hh[64 + dim];
  const float bin_ = b_ih[128 + dim];
  const float bhn  = b_hh[128 + dim];
  const float ow   = out_W[dim];
  const float histb = hist_b[0];

  float lacc[4] = {0.f, 0.f, 0.f, 0.f};
  float il = 0.f;

  __syncthreads();

  #pragma unroll 1
  for (int t = 0; t < Tn; ++t) {
    const float srm = rmsum[t];

    // ---- Ph1: wave0 = history regression; waves1-3 = load inputs ----
    if (w == 0) {
      const int r = lane & 15, kq = lane >> 4;
      float p = 0.f;
      #pragma unroll
      for (int k = 0; k < 16; ++k) p += h_s[r * HLST + kq * 16 + k] * histw_s[kq * 16 + k];
      p += __shfl_xor(p, 16);
      p += __shfl_xor(p, 32);
      if (lane < 16) vx_s[r] = p + histb;
    } else {
      const int u = tid - 64;
      const int r = u & 15, db3 = u >> 4;         // db3 in [0,12)
      const size_t base = ((size_t)(row0 + r) * Tn + t) * Dn;
      #pragma unroll
      for (int j = 0; j < 3; ++j) {
        int d = db3 + 12 * j;
        float v  = values[base + d];
        float m  = masks[base + d];
        float dl = deltas[base + d];
        val_s[r * 37 + d] = v;
        msk_s[r * 37 + d] = m;
        dbuf[r * DST + d] = f2bf(dl);
        short mb = f2bf(m);
        cbuf[r * CST + 36 + d] = mb;
        xbuf[r * XST + 36 + d] = mb;
      }
    }
    __syncthreads();

    // ---- Ph2: il_x, value_c1 ----
    {
      const int r = tid & 15, dbase = tid >> 4;
      const float vx = vx_s[r];
      for (int d = dbase; d < Dn; d += 16) {
        float v = val_s[r * 37 + d], m = msk_s[r * 37 + d];
        il += srm * fabsf(vx - v) * m;
        float vc = m * v + (1.f - m) * vx;
        vcbuf[r * DST + d] = f2bf(vc);
      }
    }
    __syncthreads();

    // ---- Ph3: gamma (decay) and value_z (feat) GEMMs ----
    f32x4 accz = {0.f, 0.f, 0.f, 0.f};
    if (w < 3) {
      f32x4 accg = {0.f, 0.f, 0.f, 0.f};
      #pragma unroll
      for (int kt = 0; kt < 2; ++kt) {
        s8 a  = *(const s8*)&dbuf[lc * DST + k0b + 32 * kt];
        accg = __builtin_amdgcn_mfma_f32_16x16x32_bf16(a, dec_f[kt], accg, 0, 0, 0);
        s8 av = *(const s8*)&vcbuf[lc * DST + k0b + 32 * kt];
        accz = __builtin_amdgcn_mfma_f32_16x16x32_bf16(av, feat_f[kt], accz, 0, 0, 0);
      }
      if (nsm < Dn) {
        #pragma unroll
        for (int q = 0; q < 4; ++q) {
          int rr = r4 * 4 + q;
          float g = __expf(-fmaxf(accg[q] + db, 0.f));
          short gb = f2bf(g);
          cbuf[rr * CST + nsm] = gb;
          xbuf[rr * XST + 72 + nsm] = gb;
        }
      }
    }
    __syncthreads();

    // ---- Ph4: beta (comb) GEMM, imputation chain, store output ----
    if (w < 3) {
      f32x4 accb = {0.f, 0.f, 0.f, 0.f};
      #pragma unroll
      for (int kt = 0; kt < 3; ++kt) {
        s8 a = *(const s8*)&cbuf[lc * CST + k0b + 32 * kt];
        accb = __builtin_amdgcn_mfma_f32_16x16x32_bf16(a, comb_f[kt], accb, 0, 0, 0);
      }
      if (nsm < Dn) {
        #pragma unroll
        for (int q = 0; q < 4; ++q) {
          int rr = r4 * 4 + q;
          float beta = sigf(accb[q] + cbv);
          float vz = accz[q] + fb;
          float v  = val_s[rr * 37 + nsm];
          float m  = msk_s[rr * 37 + nsm];
          float vx = vx_s[rr];
          il += srm * fabsf(vz - v) * m;
          float vh = vz * beta + vx * (1.f - beta);
          il += srm * fabsf(vh - v) * m;
          float vc2 = m * v + (1.f - m) * vh;
          out[1 + ((size_t)(row0 + rr) * Tn + t) * Dn + nsm] = vc2;
          xbuf[rr * XST + nsm] = f2bf(vc2);
        }
      }
    }
    __syncthreads();

    // ---- Ph5a: GRU gate GEMMs (all 4 waves) ----
    f32x4 ar = {0.f,0.f,0.f,0.f}, az = {0.f,0.f,0.f,0.f};
    f32x4 an = {0.f,0.f,0.f,0.f}, ahn = {0.f,0.f,0.f,0.f};
    #pragma unroll
    for (int kt = 0; kt < 4; ++kt) {
      s8 a = *(const s8*)&xbuf[lc * XST + k0b + 32 * kt];
      ar = __builtin_amdgcn_mfma_f32_16x16x32_bf16(a, wih_f[0][kt], ar, 0, 0, 0);
      az = __builtin_amdgcn_mfma_f32_16x16x32_bf16(a, wih_f[1][kt], az, 0, 0, 0);
      an = __builtin_amdgcn_mfma_f32_16x16x32_bf16(a, wih_f[2][kt], an, 0, 0, 0);
    }
    #pragma unroll
    for (int kt = 0; kt < 2; ++kt) {
      s8 a = *(const s8*)&hbuf[lc * DST + k0b + 32 * kt];
      ar  = __builtin_amdgcn_mfma_f32_16x16x32_bf16(a, whh_f[0][kt], ar, 0, 0, 0);
      az  = __builtin_amdgcn_mfma_f32_16x16x32_bf16(a, whh_f[1][kt], az, 0, 0, 0);
      ahn = __builtin_amdgcn_mfma_f32_16x16x32_bf16(a, whh_f[2][kt], ahn, 0, 0, 0);
    }
    __syncthreads();  // all hbuf reads complete before h writes

    // ---- Ph5b: GRU elementwise update ----
    #pragma unroll
    for (int q = 0; q < 4; ++q) {
      int rr = r4 * 4 + q;
      float hold = h_s[rr * HLST + dim];
      float rg = sigf(ar[q] + br);
      float zg = sigf(az[q] + bz);
      float ng = tanhfast(an[q] + bin_ + rg * (ahn[q] + bhn));
      float hn = (1.f - zg) * ng + zg * hold;
      lacc[q] += hn * ow;
      h_s[rr * HLST + dim] = hn;
      hbuf[rr * DST + dim] = f2bf(hn);
    }
    __syncthreads();  // end of step
  }

  // ---- epilogue: reduce il, logits, pred, class loss ----
  red_s[tid] = il;
  __syncthreads();
  for (int k = 128; k > 0; k >>= 1) {
    if (tid < k) red_s[tid] += red_s[tid + k];
    __syncthreads();
  }
  if (tid == 0) atomicAdd(&ws_acc[0], red_s[0]);
  __syncthreads();

  if (tid < 16) red_s[tid] = 0.f;
  __syncthreads();
  #pragma unroll
  for (int q = 0; q < 4; ++q) atomicAdd(&red_s[r4 * 4 + q], lacc[q]);
  __syncthreads();

  if (tid < 16) {
    float lg = red_s[tid] / (float)Tn + out_b[0];
    int rg = row0 + tid;
    float pred = sigf(lg);
    out[1 + (size_t)Bsz * Tn * Dn + rg] = pred;
    float y = label[rg], wt = is_train[rg];
    float bce = fmaxf(lg, 0.f) - lg * y + log1pf(__expf(-fabsf(lg)));
    atomicAdd(&ws_acc[1], bce * wt);
    atomicAdd(&ws_acc[2], wt);
  }
}

// ---------------- finalize loss -------------------------------------------------
__global__ void fin_k(const float* __restrict__ ws, float* __restrict__ out) {
  out[0] = ws[1] / (ws[2] + EPSf) + ws[0] / (float)Tn;
}

extern "C" void kernel_launch(void* const* d_in, const int* in_sizes, int n_in,
                              void* d_out, int out_size, void* d_ws, size_t ws_size,
                              hipStream_t stream) {
  const float* values   = (const float*)d_in[0];
  const float* masks    = (const float*)d_in[1];
  const float* deltas   = (const float*)d_in[2];
  const float* label    = (const float*)d_in[3];
  const float* is_train = (const float*)d_in[4];
  const float* W_ih     = (const float*)d_in[5];
  const float* W_hh     = (const float*)d_in[6];
  const float* b_ih     = (const float*)d_in[7];
  const float* b_hh     = (const float*)d_in[8];
  const float* hist_W   = (const float*)d_in[9];
  const float* hist_b   = (const float*)d_in[10];
  const float* feat_W   = (const float*)d_in[11];
  const float* feat_b   = (const float*)d_in[12];
  const float* decay_W  = (const float*)d_in[13];
  const float* decay_b  = (const float*)d_in[14];
  const float* comb_W   = (const float*)d_in[15];
  const float* comb_b   = (const float*)d_in[16];
  const float* out_W    = (const float*)d_in[17];
  const float* out_b    = (const float*)d_in[18];

  float* ws = (float*)d_ws;
  float* rmsum = ws + 4;
  float* out = (float*)d_out;

  hipMemsetAsync(d_ws, 0, 16, stream);                 // zero il/cls/wsum accumulators
  msum_k<<<Tn, 256, 0, stream>>>(masks, rmsum);
  brits_main<<<Bsz / 16, 256, 0, stream>>>(
      values, masks, deltas, label, is_train, W_ih, W_hh, b_ih, b_hh,
      hist_W, hist_b, feat_W, feat_b, decay_W, decay_b, comb_W, comb_b,
      out_W, out_b, out, rmsum, ws);
  fin_k<<<1, 1, 0, stream>>>(ws, out);
}

// Round 2
// 723.075 us; speedup vs baseline: 1.1680x; 1.1680x over previous
//
#include <hip/hip_runtime.h>

// BRITS-style RNN (B=4096, T=256, D=36, H=64) on gfx950.
// R1 design: 512 blocks x 256 threads; block owns 8 rows (M=16 MFMA half-padded)
// -> 2 blocks/CU for cross-block latency hiding. Register prefetch of step t+1
// inputs during step t. 4 barriers/step (was 6): gh GEMM moved to gamma phase,
// value_c computed from prefetch regs, GRU update barrier-free after gi.

#define Bsz 4096
#define Tn  256
#define Dn  36
#define Hn  64
#define ROWS 8
#define EPSf 1e-5f

// LDS strides (elements)
#define DST 72    // dbuf / vcbuf / hbuf (shorts): 36 or 64 data + zero pad
#define CST 104   // cbuf (shorts): 72 data + zero pad to 96 + pad
#define XST 136   // xbuf (shorts): 108 data + zero pad to 128 + pad
#define HLST 65   // h_s (floats)

using f32x4 = __attribute__((ext_vector_type(4))) float;
using s8    = __attribute__((ext_vector_type(8))) short;

__device__ __forceinline__ short f2bf(float x) {
  unsigned u = __float_as_uint(x);
  unsigned r = (u + 0x7FFFu + ((u >> 16) & 1u)) >> 16;  // RNE
  return (short)r;
}
__device__ __forceinline__ float sigf(float x) { return 1.f / (1.f + __expf(-x)); }
__device__ __forceinline__ float tanhfast(float x) { return 1.f - 2.f / (1.f + __expf(2.f * x)); }

// ---------------- prepass: rmsum[t] = 1/(sum(masks[:,t,:]) + EPS) -------------
__global__ void msum_k(const float4* __restrict__ masks4, float* __restrict__ rmsum) {
  int t = blockIdx.x;
  float s = 0.f;
  for (int r = threadIdx.x; r < Bsz; r += 256) {
    const float4* mp = masks4 + ((size_t)r * Tn + t) * 9;
    #pragma unroll
    for (int j = 0; j < 9; ++j) { float4 v = mp[j]; s += v.x + v.y + v.z + v.w; }
  }
  __shared__ float red[256];
  red[threadIdx.x] = s;
  __syncthreads();
  for (int k = 128; k > 0; k >>= 1) {
    if (threadIdx.x < k) red[threadIdx.x] += red[threadIdx.x + k];
    __syncthreads();
  }
  if (threadIdx.x == 0) rmsum[t] = 1.f / (red[0] + EPSf);
}

// ---------------- main ---------------------------------------------------------
__global__ __launch_bounds__(256, 2) void brits_main(
    const float* __restrict__ values, const float* __restrict__ masks,
    const float* __restrict__ deltas, const float* __restrict__ label,
    const float* __restrict__ is_train,
    const float* __restrict__ W_ih, const float* __restrict__ W_hh,
    const float* __restrict__ b_ih, const float* __restrict__ b_hh,
    const float* __restrict__ hist_W, const float* __restrict__ hist_b,
    const float* __restrict__ feat_W, const float* __restrict__ feat_b,
    const float* __restrict__ decay_W, const float* __restrict__ decay_b,
    const float* __restrict__ comb_W, const float* __restrict__ comb_b,
    const float* __restrict__ out_W, const float* __restrict__ out_b,
    float* __restrict__ out, const float* __restrict__ rmsum,
    float* __restrict__ ws_acc /* [0] il, [1] cls, [2] wsum */) {

  __shared__ float val_s[ROWS * 37];
  __shared__ float msk_s[ROWS * 37];
  __shared__ float h_s[ROWS * HLST];
  __shared__ float vx_s[16];          // rows 8..15 stay 0 (read by padded lanes)
  __shared__ float histw_s[64];
  __shared__ float red_s[256];
  __shared__ short dbuf[16 * DST];    // rows 8..15 stay 0
  __shared__ short vcbuf[16 * DST];
  __shared__ short cbuf[16 * CST];
  __shared__ short xbuf[16 * XST];
  __shared__ short hbuf[16 * DST];

  const int tid  = threadIdx.x;
  const int w    = tid >> 6;        // wave 0..3
  const int lane = tid & 63;
  const int lc   = lane & 15;       // A-row / B-col / D-col
  const int r4   = lane >> 4;       // k-group (A/B), row-group (D)
  const int bid  = blockIdx.x;
  const int row0 = bid * ROWS;

  // loader mapping: set A = (pr, pdc) covers d 0..31 of 8 rows; set B (tid<32) d 32..35
  const int  pr   = tid >> 5;
  const int  pdc  = tid & 31;
  const int  pr2  = tid >> 2;
  const int  pdc2 = 32 + (tid & 3);
  const bool hasB = (tid < 32);

  // ---- init LDS ----
  for (int i = tid; i < 16 * DST; i += 256) { dbuf[i] = 0; vcbuf[i] = 0; hbuf[i] = 0; }
  for (int i = tid; i < 16 * CST; i += 256) cbuf[i] = 0;
  for (int i = tid; i < 16 * XST; i += 256) xbuf[i] = 0;
  for (int i = tid; i < ROWS * HLST; i += 256) h_s[i] = 0.f;
  for (int i = tid; i < ROWS * 37; i += 256) { val_s[i] = 0.f; msk_s[i] = 0.f; }
  if (tid < 16) vx_s[tid] = 0.f;
  if (tid < 64) histw_s[tid] = hist_W[tid];

  // ---- weight fragments (persistent VGPRs) ----
  // b[e] = W^T[k=(lane>>4)*8 + 32*kt + e][n=16*ntile + lc]
  const int k0b = r4 * 8;
  s8 wih_f[3][4];
  s8 whh_f[3][2];
  #pragma unroll
  for (int g = 0; g < 3; ++g) {
    const int n = 64 * g + 16 * w + lc;
    #pragma unroll
    for (int kt = 0; kt < 4; ++kt) {
      s8 f;
      #pragma unroll
      for (int e = 0; e < 8; ++e) {
        int k = k0b + 32 * kt + e;
        f[e] = (k < 108) ? f2bf(W_ih[n * 108 + k]) : (short)0;
      }
      wih_f[g][kt] = f;
    }
    #pragma unroll
    for (int kt = 0; kt < 2; ++kt) {
      s8 f;
      #pragma unroll
      for (int e = 0; e < 8; ++e) {
        int k = k0b + 32 * kt + e;
        f[e] = f2bf(W_hh[n * 64 + k]);
      }
      whh_f[g][kt] = f;
    }
  }
  const int  nsm = 16 * w + lc;
  const bool act = (w < 3) && (nsm < Dn);
  s8 dec_f[2], feat_f[2], comb_f[3];
  #pragma unroll
  for (int kt = 0; kt < 2; ++kt) {
    s8 fd, ff;
    #pragma unroll
    for (int e = 0; e < 8; ++e) {
      int k = k0b + 32 * kt + e;
      float dv = (act && k < Dn) ? decay_W[nsm * Dn + k] : 0.f;
      float fv = (act && k < Dn && k != nsm) ? feat_W[nsm * Dn + k] : 0.f;  // zero diag
      fd[e] = f2bf(dv);
      ff[e] = f2bf(fv);
    }
    dec_f[kt] = fd; feat_f[kt] = ff;
  }
  #pragma unroll
  for (int kt = 0; kt < 3; ++kt) {
    s8 f;
    #pragma unroll
    for (int e = 0; e < 8; ++e) {
      int k = k0b + 32 * kt + e;
      f[e] = (act && k < 72) ? f2bf(comb_W[nsm * 72 + k]) : (short)0;
    }
    comb_f[kt] = f;
  }

  const int dim = 16 * w + lc;                       // h dim, < 64
  const float db   = act ? decay_b[nsm] : 0.f;
  const float fb   = act ? feat_b[nsm] : 0.f;
  const float cbv  = act ? comb_b[nsm] : 0.f;
  const float br   = b_ih[dim] + b_hh[dim];
  const float bz   = b_ih[64 + dim] + b_hh[64 + dim];
  const float bin_ = b_ih[128 + dim];
  const float bhn  = b_hh[128 + dim];
  const float ow   = out_W[dim];
  const float histb = hist_b[0];

  float lacc[4] = {0.f, 0.f, 0.f, 0.f};
  float il = 0.f;

  // ---- prologue: load t=0 inputs into regs ----
  float cv0, cm0, cd0, cv1 = 0.f, cm1 = 0.f, cd1 = 0.f;
  {
    size_t a0 = ((size_t)(row0 + pr) * Tn) * Dn + pdc;
    cv0 = values[a0]; cm0 = masks[a0]; cd0 = deltas[a0];
    if (hasB) {
      size_t a1 = ((size_t)(row0 + pr2) * Tn) * Dn + pdc2;
      cv1 = values[a1]; cm1 = masks[a1]; cd1 = deltas[a1];
    }
  }

  __syncthreads();

  #pragma unroll 1
  for (int t = 0; t < Tn; ++t) {
    const float srm = rmsum[t];

    // ---- PhA: stage step-t regs -> LDS; wave0 also computes vx; prefetch t+1 ----
    val_s[pr * 37 + pdc] = cv0;
    msk_s[pr * 37 + pdc] = cm0;
    dbuf[pr * DST + pdc] = f2bf(cd0);
    { short mb = f2bf(cm0); cbuf[pr * CST + 36 + pdc] = mb; xbuf[pr * XST + 36 + pdc] = mb; }
    if (hasB) {
      val_s[pr2 * 37 + pdc2] = cv1;
      msk_s[pr2 * 37 + pdc2] = cm1;
      dbuf[pr2 * DST + pdc2] = f2bf(cd1);
      short mb = f2bf(cm1); cbuf[pr2 * CST + 36 + pdc2] = mb; xbuf[pr2 * XST + 36 + pdc2] = mb;
    }
    if (w == 0) {  // vx = h @ hist_W^T + hist_b  (8 rows, 8 lanes each over 64 dims)
      const int r = lane & 7, kq = lane >> 3;
      float p = 0.f;
      #pragma unroll
      for (int k = 0; k < 8; ++k) p += h_s[r * HLST + kq * 8 + k] * histw_s[kq * 8 + k];
      p += __shfl_xor(p, 8);
      p += __shfl_xor(p, 16);
      p += __shfl_xor(p, 32);
      if (lane < 8) vx_s[r] = p + histb;
    }
    // prefetch t+1 into registers (consumed next step's PhA; not on this step's path)
    float nv0 = 0.f, nm0 = 0.f, nd0 = 0.f, nv1 = 0.f, nm1 = 0.f, nd1 = 0.f;
    if (t + 1 < Tn) {
      size_t a0 = ((size_t)(row0 + pr) * Tn + (t + 1)) * Dn + pdc;
      nv0 = values[a0]; nm0 = masks[a0]; nd0 = deltas[a0];
      if (hasB) {
        size_t a1 = ((size_t)(row0 + pr2) * Tn + (t + 1)) * Dn + pdc2;
        nv1 = values[a1]; nm1 = masks[a1]; nd1 = deltas[a1];
      }
    }
    __syncthreads();  // b1

    // ---- PhB: gh GEMM (all waves) + gamma GEMM (w<3) + value_c1 from regs ----
    f32x4 ar = {0.f,0.f,0.f,0.f}, az = {0.f,0.f,0.f,0.f}, ahn = {0.f,0.f,0.f,0.f};
    #pragma unroll
    for (int kt = 0; kt < 2; ++kt) {
      s8 a = *(const s8*)&hbuf[lc * DST + k0b + 32 * kt];
      ar  = __builtin_amdgcn_mfma_f32_16x16x32_bf16(a, whh_f[0][kt], ar, 0, 0, 0);
      az  = __builtin_amdgcn_mfma_f32_16x16x32_bf16(a, whh_f[1][kt], az, 0, 0, 0);
      ahn = __builtin_amdgcn_mfma_f32_16x16x32_bf16(a, whh_f[2][kt], ahn, 0, 0, 0);
    }
    f32x4 accg = {0.f, 0.f, 0.f, 0.f};
    if (w < 3) {
      #pragma unroll
      for (int kt = 0; kt < 2; ++kt) {
        s8 a = *(const s8*)&dbuf[lc * DST + k0b + 32 * kt];
        accg = __builtin_amdgcn_mfma_f32_16x16x32_bf16(a, dec_f[kt], accg, 0, 0, 0);
      }
    }
    {
      const float vxA = vx_s[pr];
      il += srm * fabsf(vxA - cv0) * cm0;
      vcbuf[pr * DST + pdc] = f2bf(cm0 * cv0 + (1.f - cm0) * vxA);
      if (hasB) {
        const float vxB = vx_s[pr2];
        il += srm * fabsf(vxB - cv1) * cm1;
        vcbuf[pr2 * DST + pdc2] = f2bf(cm1 * cv1 + (1.f - cm1) * vxB);
      }
    }
    if (w < 3 && nsm < Dn && r4 < 2) {
      #pragma unroll
      for (int q = 0; q < 4; ++q) {
        int rr = r4 * 4 + q;  // < 8
        float g = __expf(-fmaxf(accg[q] + db, 0.f));
        short gb = f2bf(g);
        cbuf[rr * CST + nsm] = gb;
        xbuf[rr * XST + 72 + nsm] = gb;
      }
    }
    __syncthreads();  // b2

    // ---- PhC: feat + comb GEMMs, imputation chain, store, xbuf vc2 ----
    if (w < 3) {
      f32x4 accz = {0.f,0.f,0.f,0.f}, accb = {0.f,0.f,0.f,0.f};
      #pragma unroll
      for (int kt = 0; kt < 2; ++kt) {
        s8 av = *(const s8*)&vcbuf[lc * DST + k0b + 32 * kt];
        accz = __builtin_amdgcn_mfma_f32_16x16x32_bf16(av, feat_f[kt], accz, 0, 0, 0);
      }
      #pragma unroll
      for (int kt = 0; kt < 3; ++kt) {
        s8 ac = *(const s8*)&cbuf[lc * CST + k0b + 32 * kt];
        accb = __builtin_amdgcn_mfma_f32_16x16x32_bf16(ac, comb_f[kt], accb, 0, 0, 0);
      }
      if (nsm < Dn && r4 < 2) {
        #pragma unroll
        for (int q = 0; q < 4; ++q) {
          int rr = r4 * 4 + q;  // < 8
          float beta = sigf(accb[q] + cbv);
          float vz = accz[q] + fb;
          float v  = val_s[rr * 37 + nsm];
          float m  = msk_s[rr * 37 + nsm];
          float vx = vx_s[rr];
          il += srm * fabsf(vz - v) * m;
          float vh = vz * beta + vx * (1.f - beta);
          il += srm * fabsf(vh - v) * m;
          float vc2 = m * v + (1.f - m) * vh;
          out[1 + ((size_t)(row0 + rr) * Tn + t) * Dn + nsm] = vc2;
          xbuf[rr * XST + nsm] = f2bf(vc2);
        }
      }
    }
    __syncthreads();  // b3

    // ---- PhD: gi GEMMs (all 4 waves) ----
    f32x4 an = {0.f,0.f,0.f,0.f};
    #pragma unroll
    for (int kt = 0; kt < 4; ++kt) {
      s8 a = *(const s8*)&xbuf[lc * XST + k0b + 32 * kt];
      ar = __builtin_amdgcn_mfma_f32_16x16x32_bf16(a, wih_f[0][kt], ar, 0, 0, 0);
      az = __builtin_amdgcn_mfma_f32_16x16x32_bf16(a, wih_f[1][kt], az, 0, 0, 0);
      an = __builtin_amdgcn_mfma_f32_16x16x32_bf16(a, wih_f[2][kt], an, 0, 0, 0);
    }

    // ---- PhE: GRU elementwise update (no barrier needed after PhD) ----
    if (r4 < 2) {
      #pragma unroll
      for (int q = 0; q < 4; ++q) {
        int rr = r4 * 4 + q;  // < 8
        float hold = h_s[rr * HLST + dim];
        float rg = sigf(ar[q] + br);
        float zg = sigf(az[q] + bz);
        float ng = tanhfast(an[q] + bin_ + rg * (ahn[q] + bhn));
        float hn = (1.f - zg) * ng + zg * hold;
        lacc[q] += hn * ow;
        h_s[rr * HLST + dim] = hn;
        hbuf[rr * DST + dim] = f2bf(hn);
      }
    }

    // rotate prefetch registers
    cv0 = nv0; cm0 = nm0; cd0 = nd0;
    cv1 = nv1; cm1 = nm1; cd1 = nd1;
    __syncthreads();  // b4 (end of step)
  }

  // ---- epilogue: reduce il, logits, pred, class loss ----
  red_s[tid] = il;
  __syncthreads();
  for (int k = 128; k > 0; k >>= 1) {
    if (tid < k) red_s[tid] += red_s[tid + k];
    __syncthreads();
  }
  if (tid == 0) atomicAdd(&ws_acc[0], red_s[0]);
  __syncthreads();

  if (tid < ROWS) red_s[tid] = 0.f;
  __syncthreads();
  if (r4 < 2) {
    #pragma unroll
    for (int q = 0; q < 4; ++q) atomicAdd(&red_s[r4 * 4 + q], lacc[q]);
  }
  __syncthreads();

  if (tid < ROWS) {
    float lg = red_s[tid] / (float)Tn + out_b[0];
    int rg = row0 + tid;
    float pred = sigf(lg);
    out[1 + (size_t)Bsz * Tn * Dn + rg] = pred;
    float y = label[rg], wt = is_train[rg];
    float bce = fmaxf(lg, 0.f) - lg * y + log1pf(__expf(-fabsf(lg)));
    atomicAdd(&ws_acc[1], bce * wt);
    atomicAdd(&ws_acc[2], wt);
  }
}

// ---------------- finalize loss -------------------------------------------------
__global__ void fin_k(const float* __restrict__ ws, float* __restrict__ out) {
  out[0] = ws[1] / (ws[2] + EPSf) + ws[0] / (float)Tn;
}

extern "C" void kernel_launch(void* const* d_in, const int* in_sizes, int n_in,
                              void* d_out, int out_size, void* d_ws, size_t ws_size,
                              hipStream_t stream) {
  const float* values   = (const float*)d_in[0];
  const float* masks    = (const float*)d_in[1];
  const float* deltas   = (const float*)d_in[2];
  const float* label    = (const float*)d_in[3];
  const float* is_train = (const float*)d_in[4];
  const float* W_ih     = (const float*)d_in[5];
  const float* W_hh     = (const float*)d_in[6];
  const float* b_ih     = (const float*)d_in[7];
  const float* b_hh     = (const float*)d_in[8];
  const float* hist_W   = (const float*)d_in[9];
  const float* hist_b   = (const float*)d_in[10];
  const float* feat_W   = (const float*)d_in[11];
  const float* feat_b   = (const float*)d_in[12];
  const float* decay_W  = (const float*)d_in[13];
  const float* decay_b  = (const float*)d_in[14];
  const float* comb_W   = (const float*)d_in[15];
  const float* comb_b   = (const float*)d_in[16];
  const float* out_W    = (const float*)d_in[17];
  const float* out_b    = (const float*)d_in[18];

  float* ws = (float*)d_ws;
  float* rmsum = ws + 4;
  float* out = (float*)d_out;

  hipMemsetAsync(d_ws, 0, 16, stream);
  msum_k<<<Tn, 256, 0, stream>>>((const float4*)masks, rmsum);
  brits_main<<<Bsz / ROWS, 256, 0, stream>>>(
      values, masks, deltas, label, is_train, W_ih, W_hh, b_ih, b_hh,
      hist_W, hist_b, feat_W, feat_b, decay_W, decay_b, comb_W, comb_b,
      out_W, out_b, out, rmsum, ws);
  fin_k<<<1, 1, 0, stream>>>(ws, out);
}

// Round 3
// 512.068 us; speedup vs baseline: 1.6494x; 1.4121x over previous
//
#include <hip/hip_runtime.h>

// BRITS-style RNN (B=4096, T=256, D=36, H=64) on gfx950.
// R3: 256 blocks x 512 threads (8 waves), 16 rows/block, full M=16 MFMA packing.
// Waves 0-3 ("G"): gate dims 16w..16w+15 for r,z,n (gh+gi MFMA, GRU update, h in regs).
// Waves 4-7 ("S"): gamma/feat/comb small GEMMs, staging, vx (aux MFMA on wave7), impute.
// gi split by K-tile readiness across phases; xbuf = [mask|gamma|vc2] with remapped
// weights (comb reads stale vc2 slots x zero weight = benign). All MFMA A-buffers in
// fragment-linear LDS layout (lane*16B contiguous) -> conflict-free ds_read_b128.

#define Bsz 4096
#define Tn  256
#define Dn  36
#define ROWS 16
#define EPSf 1e-5f
#define VMST 38

using f32x4 = __attribute__((ext_vector_type(4))) float;
using s8    = __attribute__((ext_vector_type(8))) short;

__device__ __forceinline__ short f2bf(float x) {
  unsigned u = __float_as_uint(x);
  unsigned r = (u + 0x7FFFu + ((u >> 16) & 1u)) >> 16;  // RNE
  return (short)r;
}
__device__ __forceinline__ float sigf(float x) { return 1.f / (1.f + __expf(-x)); }
__device__ __forceinline__ float tanhfast(float x) { return 1.f - 2.f / (1.f + __expf(2.f * x)); }
// fragment-linear offset for element (row, k) of an MFMA A-tile (16 rows, bf16):
// lane = ((k%32)/8)*16 + row, addr = (k/32)*512 + lane*8 + k%8
__device__ __forceinline__ int fragoff(int row, int k) {
  return ((k >> 5) << 9) + (((k >> 3) & 3) << 7) + (row << 3) + (k & 7);
}

// ---------------- prepass: rmsum[t] = 1/(sum(masks[:,t,:]) + EPS) -------------
__global__ void msum_k(const float4* __restrict__ masks4, float* __restrict__ rmsum) {
  int t = blockIdx.x;
  float s = 0.f;
  for (int r = threadIdx.x; r < Bsz; r += 256) {
    const float4* mp = masks4 + ((size_t)r * Tn + t) * 9;
    #pragma unroll
    for (int j = 0; j < 9; ++j) { float4 v = mp[j]; s += v.x + v.y + v.z + v.w; }
  }
  __shared__ float red[256];
  red[threadIdx.x] = s;
  __syncthreads();
  for (int k = 128; k > 0; k >>= 1) {
    if (threadIdx.x < k) red[threadIdx.x] += red[threadIdx.x + k];
    __syncthreads();
  }
  if (threadIdx.x == 0) rmsum[t] = 1.f / (red[0] + EPSf);
}

// ---------------- main ---------------------------------------------------------
__global__ __launch_bounds__(512, 2) void brits_main(
    const float* __restrict__ values, const float* __restrict__ masks,
    const float* __restrict__ deltas, const float* __restrict__ label,
    const float* __restrict__ is_train,
    const float* __restrict__ W_ih, const float* __restrict__ W_hh,
    const float* __restrict__ b_ih, const float* __restrict__ b_hh,
    const float* __restrict__ hist_W, const float* __restrict__ hist_b,
    const float* __restrict__ feat_W, const float* __restrict__ feat_b,
    const float* __restrict__ decay_W, const float* __restrict__ decay_b,
    const float* __restrict__ comb_W, const float* __restrict__ comb_b,
    const float* __restrict__ out_W, const float* __restrict__ out_b,
    float* __restrict__ out, const float* __restrict__ rmsum,
    float* __restrict__ ws_acc /* [0] il, [1] cls, [2] wsum */) {

  __shared__ float2 vm_s[ROWS * VMST];   // (value, mask) f32 pairs, row-major
  __shared__ float  vx_s[ROWS];
  __shared__ float  red_s[512];
  __shared__ float  red16[ROWS];
  __shared__ short  dbuf[1024];          // delta,  K=64  (frag-linear, [36,64) zero)
  __shared__ short  vcbuf[1024];         // vc1,    K=64  (frag-linear, [36,64) zero)
  __shared__ short  hbuf[1024];          // h bf16, K=64  (frag-linear)
  __shared__ short  xbuf[2048];          // [mask(0:36)|gamma(36:72)|vc2(72:108)|0], K=128

  const int tid  = threadIdx.x;
  const int w    = tid >> 6;        // wave 0..7
  const int lane = tid & 63;
  const int lc   = lane & 15;
  const int r4   = lane >> 4;
  const bool isG = (w < 4);
  const int row0 = blockIdx.x * ROWS;
  const int k0b  = r4 * 8;

  // ---- weight fragments (persistent VGPRs, role-overlaid) ----
  // G:   bfrag[g*4+kt] = W_ih (remapped to xbuf k-space), bfrag[12+g*2+kt] = W_hh
  // S46: bfrag[0..1]=decay, [2..3]=feat(zero diag), [4..6]=comb (xbuf k-space remap)
  // S7:  bfrag[0..1] = hist aux (col 0 only)
  s8 bfrag[18];
  #pragma unroll
  for (int i = 0; i < 18; ++i) bfrag[i] = (s8)(short)0;

  float br = 0.f, bz = 0.f, bin_ = 0.f, bhn = 0.f, ow = 0.f;
  float db = 0.f, fb = 0.f, cbv = 0.f;
  int nsm = 0, dim = 0;
  const float histb = hist_b[0];

  if (isG) {
    dim = 16 * w + lc;
    #pragma unroll
    for (int g = 0; g < 3; ++g) {
      const int n = 64 * g + dim;
      #pragma unroll
      for (int kt = 0; kt < 4; ++kt) {
        s8 f;
        #pragma unroll
        for (int e = 0; e < 8; ++e) {
          int xk = k0b + 32 * kt + e;
          // xbuf k-space: [mask(0:36)|gamma(36:72)|vc2(72:108)|pad]
          // W_ih cols:    [vc(0:36)|mask(36:72)|gamma(72:108)]
          float wv = 0.f;
          if (xk < 72) wv = W_ih[n * 108 + 36 + xk];        // mask & gamma
          else if (xk < 108) wv = W_ih[n * 108 + xk - 72];  // vc2
          f[e] = f2bf(wv);
        }
        bfrag[g * 4 + kt] = f;
      }
      #pragma unroll
      for (int kt = 0; kt < 2; ++kt) {
        s8 f;
        #pragma unroll
        for (int e = 0; e < 8; ++e) f[e] = f2bf(W_hh[n * 64 + k0b + 32 * kt + e]);
        bfrag[12 + g * 2 + kt] = f;
      }
    }
    br   = b_ih[dim] + b_hh[dim];
    bz   = b_ih[64 + dim] + b_hh[64 + dim];
    bin_ = b_ih[128 + dim];
    bhn  = b_hh[128 + dim];
    ow   = out_W[dim];
  } else if (w < 7) {
    nsm = 16 * (w - 4) + lc;
    const bool act = (nsm < Dn);
    #pragma unroll
    for (int kt = 0; kt < 2; ++kt) {
      s8 fd, ff;
      #pragma unroll
      for (int e = 0; e < 8; ++e) {
        int k = k0b + 32 * kt + e;
        fd[e] = f2bf((act && k < Dn) ? decay_W[nsm * Dn + k] : 0.f);
        ff[e] = f2bf((act && k < Dn && k != nsm) ? feat_W[nsm * Dn + k] : 0.f);
      }
      bfrag[kt] = fd; bfrag[2 + kt] = ff;
    }
    #pragma unroll
    for (int kt = 0; kt < 3; ++kt) {
      s8 f;
      #pragma unroll
      for (int e = 0; e < 8; ++e) {
        int xk = k0b + 32 * kt + e;
        // comb input [gamma(0:36)|mask(36:72)]; xbuf = [mask(0:36)|gamma(36:72)|...]
        float wv = 0.f;
        if (act) {
          if (xk < 36) wv = comb_W[nsm * 72 + 36 + xk];       // mask part
          else if (xk < 72) wv = comb_W[nsm * 72 + xk - 36];  // gamma part
        }
        f[e] = f2bf(wv);
      }
      bfrag[4 + kt] = f;
    }
    db  = act ? decay_b[nsm] : 0.f;
    fb  = act ? feat_b[nsm] : 0.f;
    cbv = act ? comb_b[nsm] : 0.f;
  } else {
    #pragma unroll
    for (int kt = 0; kt < 2; ++kt) {
      s8 f;
      #pragma unroll
      for (int e = 0; e < 8; ++e)
        f[e] = (lc == 0) ? f2bf(hist_W[k0b + 32 * kt + e]) : (short)0;
      bfrag[kt] = f;
    }
  }

  // ---- S staging geometry: 576 slots (16 rows x 36 cols) over 256 S-threads ----
  const int sidx = tid - 256;
  size_t pbase[3] = {0, 0, 0};
  int vmoff[3] = {0, 0, 0}, foff[3] = {0, 0, 0}, xoff[3] = {0, 0, 0}, prow_[3] = {0, 0, 0};
  bool pval[3] = {false, false, false};
  if (!isG) {
    #pragma unroll
    for (int j = 0; j < 3; ++j) {
      int slot = sidx + 256 * j;
      pval[j] = (slot < ROWS * Dn);
      if (pval[j]) {
        int pr = slot / Dn;
        int pc = slot - pr * Dn;
        prow_[j] = pr;
        pbase[j] = ((size_t)(row0 + pr) * Tn) * Dn + pc;
        vmoff[j] = pr * VMST + pc;
        foff[j]  = fragoff(pr, pc);       // dbuf & vcbuf (same K-geometry)
        xoff[j]  = fragoff(pr, pc);       // xbuf mask region (k = pc)
      }
    }
  }

  // ---- init LDS ----
  for (int i = tid; i < 1024; i += 512) { dbuf[i] = 0; vcbuf[i] = 0; hbuf[i] = 0; }
  for (int i = tid; i < 2048; i += 512) xbuf[i] = 0;
  __syncthreads();

  // ---- prologue: stage t=0, prefetch t=1 ----
  float pv[3] = {0.f, 0.f, 0.f}, pm[3] = {0.f, 0.f, 0.f}, pd[3] = {0.f, 0.f, 0.f};
  if (!isG) {
    #pragma unroll
    for (int j = 0; j < 3; ++j) if (pval[j]) {
      float v = values[pbase[j]], m = masks[pbase[j]], d = deltas[pbase[j]];
      vm_s[vmoff[j]] = make_float2(v, m);
      dbuf[foff[j]] = f2bf(d);
      xbuf[xoff[j]] = f2bf(m);
    }
    #pragma unroll
    for (int j = 0; j < 3; ++j) if (pval[j]) {
      pv[j] = values[pbase[j] + Dn]; pm[j] = masks[pbase[j] + Dn]; pd[j] = deltas[pbase[j] + Dn];
    }
  }
  float hreg[4] = {0.f, 0.f, 0.f, 0.f};
  float lacc[4] = {0.f, 0.f, 0.f, 0.f};
  float il = 0.f;
  f32x4 A0 = {0,0,0,0}, A1 = {0,0,0,0}, A2 = {0,0,0,0}, A3 = {0,0,0,0};
  __syncthreads();

  #pragma unroll 1
  for (int t = 0; t < Tn; ++t) {
    const float srm = rmsum[t];

    // ---- PhA: G: gh GEMM; wave7: vx aux GEMM ----
    if (isG) {
      A0 = (f32x4){0,0,0,0}; A1 = (f32x4){0,0,0,0}; A2 = (f32x4){0,0,0,0}; A3 = (f32x4){0,0,0,0};
      #pragma unroll
      for (int kt = 0; kt < 2; ++kt) {
        s8 a = *(const s8*)&hbuf[kt * 512 + lane * 8];
        A0 = __builtin_amdgcn_mfma_f32_16x16x32_bf16(a, bfrag[12 + kt], A0, 0, 0, 0);
        A1 = __builtin_amdgcn_mfma_f32_16x16x32_bf16(a, bfrag[14 + kt], A1, 0, 0, 0);
        A3 = __builtin_amdgcn_mfma_f32_16x16x32_bf16(a, bfrag[16 + kt], A3, 0, 0, 0);
      }
    } else if (w == 7) {
      f32x4 X = {0,0,0,0};
      #pragma unroll
      for (int kt = 0; kt < 2; ++kt) {
        s8 a = *(const s8*)&hbuf[kt * 512 + lane * 8];
        X = __builtin_amdgcn_mfma_f32_16x16x32_bf16(a, bfrag[kt], X, 0, 0, 0);
      }
      if (lc == 0) {
        #pragma unroll
        for (int q = 0; q < 4; ++q) vx_s[r4 * 4 + q] = X[q] + histb;
      }
    }
    __syncthreads();  // b1: vx ready, t-inputs staged (prev PhD)

    // ---- PhB: S46 gamma; all-S vc1; G gi-kt0 (mask) ----
    if (isG) {
      s8 a = *(const s8*)&xbuf[lane * 8];
      A0 = __builtin_amdgcn_mfma_f32_16x16x32_bf16(a, bfrag[0], A0, 0, 0, 0);
      A1 = __builtin_amdgcn_mfma_f32_16x16x32_bf16(a, bfrag[4], A1, 0, 0, 0);
      A2 = __builtin_amdgcn_mfma_f32_16x16x32_bf16(a, bfrag[8], A2, 0, 0, 0);
    } else {
      if (w < 7) {
        f32x4 Gm = {0,0,0,0};
        #pragma unroll
        for (int kt = 0; kt < 2; ++kt) {
          s8 a = *(const s8*)&dbuf[kt * 512 + lane * 8];
          Gm = __builtin_amdgcn_mfma_f32_16x16x32_bf16(a, bfrag[kt], Gm, 0, 0, 0);
        }
        if (nsm < Dn) {
          const int gb = fragoff(0, 36 + nsm);
          #pragma unroll
          for (int q = 0; q < 4; ++q) {
            float g = __expf(-fmaxf(Gm[q] + db, 0.f));
            xbuf[gb + (r4 * 4 + q) * 8] = f2bf(g);
          }
        }
      }
      #pragma unroll
      for (int j = 0; j < 3; ++j) if (pval[j]) {
        float2 vm = vm_s[vmoff[j]];
        float vx = vx_s[prow_[j]];
        il += srm * fabsf(vx - vm.x) * vm.y;
        vcbuf[foff[j]] = f2bf(vm.y * vm.x + (1.f - vm.y) * vx);
      }
    }
    __syncthreads();  // b2: gamma + vc1 ready

    // ---- PhC: S46 feat+comb GEMMs + impute chain; G gi-kt1 (gamma) ----
    if (isG) {
      s8 a = *(const s8*)&xbuf[512 + lane * 8];
      A0 = __builtin_amdgcn_mfma_f32_16x16x32_bf16(a, bfrag[1], A0, 0, 0, 0);
      A1 = __builtin_amdgcn_mfma_f32_16x16x32_bf16(a, bfrag[5], A1, 0, 0, 0);
      A2 = __builtin_amdgcn_mfma_f32_16x16x32_bf16(a, bfrag[9], A2, 0, 0, 0);
    } else if (w < 7) {
      f32x4 Z = {0,0,0,0}, Bc = {0,0,0,0};
      #pragma unroll
      for (int kt = 0; kt < 2; ++kt) {
        s8 av = *(const s8*)&vcbuf[kt * 512 + lane * 8];
        Z = __builtin_amdgcn_mfma_f32_16x16x32_bf16(av, bfrag[2 + kt], Z, 0, 0, 0);
      }
      #pragma unroll
      for (int kt = 0; kt < 3; ++kt) {
        s8 ac = *(const s8*)&xbuf[kt * 512 + lane * 8];
        Bc = __builtin_amdgcn_mfma_f32_16x16x32_bf16(ac, bfrag[4 + kt], Bc, 0, 0, 0);
      }
      if (nsm < Dn) {
        const int vb = fragoff(0, 72 + nsm);
        #pragma unroll
        for (int q = 0; q < 4; ++q) {
          int rr = r4 * 4 + q;
          float beta = sigf(Bc[q] + cbv);
          float vz = Z[q] + fb;
          float2 vm = vm_s[rr * VMST + nsm];
          float vx = vx_s[rr];
          il += srm * fabsf(vz - vm.x) * vm.y;
          float vh = vz * beta + vx * (1.f - beta);
          il += srm * fabsf(vh - vm.x) * vm.y;
          float vc2 = vm.y * vm.x + (1.f - vm.y) * vh;
          out[1 + ((size_t)(row0 + rr) * Tn + t) * Dn + nsm] = vc2;
          xbuf[vb + rr * 8] = f2bf(vc2);
        }
      }
    }
    __syncthreads();  // b3: vc2 ready

    // ---- PhD: G gi-kt2/kt3 + GRU update; S stage t+1 + prefetch t+2 ----
    if (isG) {
      #pragma unroll
      for (int kt = 2; kt < 4; ++kt) {
        s8 a = *(const s8*)&xbuf[kt * 512 + lane * 8];
        A0 = __builtin_amdgcn_mfma_f32_16x16x32_bf16(a, bfrag[kt], A0, 0, 0, 0);
        A1 = __builtin_amdgcn_mfma_f32_16x16x32_bf16(a, bfrag[4 + kt], A1, 0, 0, 0);
        A2 = __builtin_amdgcn_mfma_f32_16x16x32_bf16(a, bfrag[8 + kt], A2, 0, 0, 0);
      }
      const int hb = fragoff(0, dim);
      #pragma unroll
      for (int q = 0; q < 4; ++q) {
        float rg = sigf(A0[q] + br);
        float zg = sigf(A1[q] + bz);
        float ng = tanhfast(A2[q] + bin_ + rg * (A3[q] + bhn));
        float hn = (1.f - zg) * ng + zg * hreg[q];
        hreg[q] = hn;
        lacc[q] += hn * ow;
        hbuf[hb + (r4 * 4 + q) * 8] = f2bf(hn);
      }
    } else {
      if (t + 1 < Tn) {
        #pragma unroll
        for (int j = 0; j < 3; ++j) if (pval[j]) {
          vm_s[vmoff[j]] = make_float2(pv[j], pm[j]);
          dbuf[foff[j]] = f2bf(pd[j]);
          xbuf[xoff[j]] = f2bf(pm[j]);
        }
      }
      if (t + 2 < Tn) {
        size_t o = (size_t)(t + 2) * Dn;
        #pragma unroll
        for (int j = 0; j < 3; ++j) if (pval[j]) {
          pv[j] = values[pbase[j] + o];
          pm[j] = masks[pbase[j] + o];
          pd[j] = deltas[pbase[j] + o];
        }
      }
    }
    __syncthreads();  // b4: end of step (hbuf + staged t+1 ready)
  }

  // ---- epilogue: reduce il, logits, pred, class loss ----
  red_s[tid] = il;
  __syncthreads();
  for (int k = 256; k > 0; k >>= 1) {
    if (tid < k) red_s[tid] += red_s[tid + k];
    __syncthreads();
  }
  if (tid == 0) atomicAdd(&ws_acc[0], red_s[0]);
  if (tid < ROWS) red16[tid] = 0.f;
  __syncthreads();
  if (isG) {
    #pragma unroll
    for (int q = 0; q < 4; ++q) atomicAdd(&red16[r4 * 4 + q], lacc[q]);
  }
  __syncthreads();

  if (tid < ROWS) {
    float lg = red16[tid] / (float)Tn + out_b[0];
    int rg = row0 + tid;
    float pred = sigf(lg);
    out[1 + (size_t)Bsz * Tn * Dn + rg] = pred;
    float y = label[rg], wt = is_train[rg];
    float bce = fmaxf(lg, 0.f) - lg * y + log1pf(__expf(-fabsf(lg)));
    atomicAdd(&ws_acc[1], bce * wt);
    atomicAdd(&ws_acc[2], wt);
  }
}

// ---------------- finalize loss -------------------------------------------------
__global__ void fin_k(const float* __restrict__ ws, float* __restrict__ out) {
  out[0] = ws[1] / (ws[2] + EPSf) + ws[0] / (float)Tn;
}

extern "C" void kernel_launch(void* const* d_in, const int* in_sizes, int n_in,
                              void* d_out, int out_size, void* d_ws, size_t ws_size,
                              hipStream_t stream) {
  const float* values   = (const float*)d_in[0];
  const float* masks    = (const float*)d_in[1];
  const float* deltas   = (const float*)d_in[2];
  const float* label    = (const float*)d_in[3];
  const float* is_train = (const float*)d_in[4];
  const float* W_ih     = (const float*)d_in[5];
  const float* W_hh     = (const float*)d_in[6];
  const float* b_ih     = (const float*)d_in[7];
  const float* b_hh     = (const float*)d_in[8];
  const float* hist_W   = (const float*)d_in[9];
  const float* hist_b   = (const float*)d_in[10];
  const float* feat_W   = (const float*)d_in[11];
  const float* feat_b   = (const float*)d_in[12];
  const float* decay_W  = (const float*)d_in[13];
  const float* decay_b  = (const float*)d_in[14];
  const float* comb_W   = (const float*)d_in[15];
  const float* comb_b   = (const float*)d_in[16];
  const float* out_W    = (const float*)d_in[17];
  const float* out_b    = (const float*)d_in[18];

  float* ws = (float*)d_ws;
  float* rmsum = ws + 4;
  float* out = (float*)d_out;

  hipMemsetAsync(d_ws, 0, 16, stream);
  msum_k<<<Tn, 256, 0, stream>>>((const float4*)masks, rmsum);
  brits_main<<<Bsz / ROWS, 512, 0, stream>>>(
      values, masks, deltas, label, is_train, W_ih, W_hh, b_ih, b_hh,
      hist_W, hist_b, feat_W, feat_b, decay_W, decay_b, comb_W, comb_b,
      out_W, out_b, out, rmsum, ws);
  fin_k<<<1, 1, 0, stream>>>(ws, out);
}